// Round 3
// baseline (251.852 us; speedup 1.0000x reference)
//
#include <hip/hip_runtime.h>
#include <hip/hip_bf16.h>

#define BN_INV 0.9999950000375f   // 1/sqrt(1+1e-5)
#define PI_F   3.14159265358979f

typedef __attribute__((ext_vector_type(8))) short s16x8;
typedef __attribute__((ext_vector_type(4))) float f32x4;
typedef __attribute__((ext_vector_type(4))) unsigned short u16x4;

__device__ inline unsigned short f2bf(float f) {
  union { float f; unsigned u; } v; v.f = f;
  unsigned r = v.u + 0x7fffu + ((v.u >> 16) & 1u);
  return (unsigned short)(r >> 16);
}

// ---------------------------------------------------------------------------
// pack: fp32 conv weights -> bf16 packed [co][k], k = kk*Ci_pad + ci
// also zero h4 (conv4 accumulates with atomics)
// ---------------------------------------------------------------------------
__global__ __launch_bounds__(256) void k_pack(
    const float* __restrict__ w1, const float* __restrict__ w2,
    const float* __restrict__ w3, const float* __restrict__ w4,
    unsigned short* __restrict__ w1p, unsigned short* __restrict__ w2p,
    unsigned short* __restrict__ w3p, unsigned short* __restrict__ w4p,
    float* __restrict__ h4)
{
  int e = blockIdx.x * 256 + threadIdx.x;
  if (e < 2048) {
    int co = e >> 6, k = e & 63, kk = k >> 3, ci = k & 7;
    w1p[e] = (ci < 4 && kk < 7) ? f2bf(w1[co * 28 + ci * 7 + kk]) : (unsigned short)0;
  } else if (e < 16384) {
    int t = e - 2048; int co = t / 224, k = t % 224, kk = k >> 5, ci = k & 31;
    w2p[t] = f2bf(w2[co * 224 + ci * 7 + kk]);
  } else if (e < 73728) {
    int t = e - 16384; int co = t / 448, k = t % 448, kk = k >> 6, ci = k & 63;
    w3p[t] = f2bf(w3[co * 448 + ci * 7 + kk]);
  } else if (e < 188416) {
    int t = e - 73728; int co = t / 896, k = t % 896, kk = k >> 7, ci = k & 127;
    w4p[t] = f2bf(w4[co * 896 + ci * 7 + kk]);
  } else if (e < 221184) {
    h4[e - 188416] = 0.f;
  }
}

// ---------------------------------------------------------------------------
// conv1 MFMA: x fp32 (256,4,3000) -> h1t bf16 [b][3000][32], BN+ReLU
// ---------------------------------------------------------------------------
__global__ __launch_bounds__(256) void k_conv1(
    const float* __restrict__ x, const unsigned short* __restrict__ w1p,
    const float* __restrict__ cb, const float* __restrict__ bng,
    const float* __restrict__ bnb, unsigned short* __restrict__ h1t)
{
  __shared__ __align__(16) char lds[520 * 16 + 4096 + 256];
  float* scs = (float*)(lds + 520 * 16 + 4096);
  const int tid = threadIdx.x;
  const int b = blockIdx.y;
  const int l0 = blockIdx.x * 512;

  for (int r = tid; r < 519; r += 256) {
    int gr = l0 + r - 3;
    s16x8 v;
    if (gr >= 0 && gr < 3000) {
      const float* xr = x + b * 4 * 3000 + gr;
      v[0] = (short)f2bf(xr[0]);
      v[1] = (short)f2bf(xr[3000]);
      v[2] = (short)f2bf(xr[6000]);
      v[3] = (short)f2bf(xr[9000]);
      v[4] = 0; v[5] = 0; v[6] = 0; v[7] = 0;
    } else {
      for (int i = 0; i < 8; ++i) v[i] = 0;
    }
    *(s16x8*)(lds + r * 16) = v;
  }
  {
    int co = tid >> 3, c = tid & 7;
    s16x8 v = *(const s16x8*)(w1p + co * 64 + c * 8);
    *(s16x8*)(lds + 8320 + ((co * 128 + c * 16) ^ ((co & 7) << 4))) = v;
  }
  if (tid < 32) {
    float sc = bng[tid] * BN_INV;
    scs[tid * 2] = sc;
    scs[tid * 2 + 1] = fmaf(cb[tid], sc, bnb[tid]);
  }
  __syncthreads();

  const int w = tid >> 6, l = tid & 63, lr = l & 15, g = l >> 4;
  const int wp = w * 128;
  f32x4 acc[2][8];
  for (int m = 0; m < 2; ++m)
    for (int n = 0; n < 8; ++n)
      for (int i = 0; i < 4; ++i) acc[m][n][i] = 0.f;

  #pragma unroll
  for (int s = 0; s < 2; ++s) {
    s16x8 a[2], bf[8];
    #pragma unroll
    for (int m = 0; m < 2; ++m) {
      int co = m * 16 + lr;
      a[m] = *(const s16x8*)(lds + 8320 + ((co * 128 + s * 64 + g * 16) ^ ((co & 7) << 4)));
    }
    #pragma unroll
    for (int n = 0; n < 8; ++n) {
      int row = wp + n * 16 + lr + s * 4 + g;
      bf[n] = *(const s16x8*)(lds + row * 16);
    }
    #pragma unroll
    for (int m = 0; m < 2; ++m)
      #pragma unroll
      for (int n = 0; n < 8; ++n)
        acc[m][n] = __builtin_amdgcn_mfma_f32_16x16x32_bf16(a[m], bf[n], acc[m][n], 0, 0, 0);
  }

  #pragma unroll
  for (int m = 0; m < 2; ++m) {
    int co0 = m * 16 + g * 4;
    float sc[4], sh[4];
    #pragma unroll
    for (int j = 0; j < 4; ++j) { sc[j] = scs[(co0 + j) * 2]; sh[j] = scs[(co0 + j) * 2 + 1]; }
    #pragma unroll
    for (int n = 0; n < 8; ++n) {
      int gp = l0 + wp + n * 16 + lr;
      if (gp < 3000) {
        u16x4 o;
        #pragma unroll
        for (int j = 0; j < 4; ++j)
          o[j] = f2bf(fmaxf(fmaf(acc[m][n][j], sc[j], sh[j]), 0.f));
        *(u16x4*)(h1t + (b * 3000 + gp) * 32 + co0) = o;
      }
    }
  }
}

// ---------------------------------------------------------------------------
// conv2 persistent: weights staged once; 4 pos-tiles of 256 with T14 prefetch
// grid (3, 256); block = co64 x pos256; wave = 4m x 4n; K=224
// ---------------------------------------------------------------------------
__global__ __launch_bounds__(256) void k_conv2(
    const unsigned short* __restrict__ h1t, const unsigned short* __restrict__ w2p,
    const float* __restrict__ cb, const float* __restrict__ bng,
    const float* __restrict__ bnb, unsigned short* __restrict__ h2pt)
{
  __shared__ __align__(16) char lds[46080];
  float* scs = (float*)(lds + 45568);
  const int tid = threadIdx.x, b = blockIdx.y, bg = blockIdx.x;

  for (int e = tid; e < 1792; e += 256) {  // weights once: 64co x 28 chunks
    int co = e / 28, c = e % 28;
    s16x8 v = *(const s16x8*)(w2p + co * 224 + c * 8);
    *(s16x8*)(lds + 16896 + ((co * 448 + c * 16) ^ ((co & 7) << 4))) = v;
  }
  if (tid < 64) {
    float sc = bng[tid] * BN_INV;
    scs[tid * 2] = sc;
    scs[tid * 2 + 1] = fmaf(cb[tid], sc, bnb[tid]);
  }
  {  // stage x tile 0
    int l0 = bg * 1024;
    #pragma unroll
    for (int i = 0; i < 5; ++i) {
      int e = tid + i * 256;
      if (e < 1048) {
        int r = e >> 2, c = e & 3, gr = l0 - 3 + r;
        s16x8 v;
        if (gr >= 0 && gr < 3000) v = *(const s16x8*)(h1t + (b * 3000 + gr) * 32 + c * 8);
        else for (int q = 0; q < 8; ++q) v[q] = 0;
        *(s16x8*)(lds + ((r * 64 + c * 16) ^ ((r & 7) << 4))) = v;
      }
    }
  }
  __syncthreads();

  const int w = tid >> 6, l = tid & 63, lr = l & 15, g = l >> 4;
  const int wp = w * 64;

  for (int t = 0; t < 4; ++t) {
    const int l0 = bg * 1024 + t * 256;

    s16x8 xr[5];
    if (t < 3) {  // T14: issue next-tile loads before compute
      int nl0 = l0 + 256;
      #pragma unroll
      for (int i = 0; i < 5; ++i) {
        for (int q = 0; q < 8; ++q) xr[i][q] = 0;
        int e = tid + i * 256;
        if (e < 1048) {
          int r = e >> 2, c = e & 3, gr = nl0 - 3 + r;
          if (gr >= 0 && gr < 3000)
            xr[i] = *(const s16x8*)(h1t + (b * 3000 + gr) * 32 + c * 8);
        }
      }
    }

    f32x4 acc[4][4];
    for (int m = 0; m < 4; ++m)
      for (int n = 0; n < 4; ++n)
        for (int i = 0; i < 4; ++i) acc[m][n][i] = 0.f;

    #pragma unroll
    for (int s = 0; s < 7; ++s) {
      s16x8 a[4], bf[4];
      #pragma unroll
      for (int m = 0; m < 4; ++m) {
        int co = m * 16 + lr;
        a[m] = *(const s16x8*)(lds + 16896 + ((co * 448 + s * 64 + g * 16) ^ ((co & 7) << 4)));
      }
      #pragma unroll
      for (int n = 0; n < 4; ++n) {
        int row = wp + n * 16 + lr + s;
        bf[n] = *(const s16x8*)(lds + ((row * 64 + g * 16) ^ ((row & 7) << 4)));
      }
      #pragma unroll
      for (int m = 0; m < 4; ++m)
        #pragma unroll
        for (int n = 0; n < 4; ++n)
          acc[m][n] = __builtin_amdgcn_mfma_f32_16x16x32_bf16(a[m], bf[n], acc[m][n], 0, 0, 0);
    }

    #pragma unroll
    for (int m = 0; m < 4; ++m) {
      int co0 = m * 16 + g * 4;
      float sc[4], sh[4];
      #pragma unroll
      for (int j = 0; j < 4; ++j) { sc[j] = scs[(co0 + j) * 2]; sh[j] = scs[(co0 + j) * 2 + 1]; }
      #pragma unroll
      for (int n = 0; n < 4; ++n) {
        u16x4 o;
        #pragma unroll
        for (int j = 0; j < 4; ++j) {
          float tv = fmaxf(fmaf(acc[m][n][j], sc[j], sh[j]), 0.f);
          float t1 = fmaxf(tv, __shfl_xor(tv, 1));
          float t2 = fmaxf(t1, __shfl_xor(t1, 2));
          o[j] = f2bf(t2);
        }
        int pp = (l0 + wp + n * 16 + lr) >> 2;
        if ((l & 3) == 0 && pp < 750)
          *(u16x4*)(h2pt + (b * 750 + pp) * 64 + co0) = o;
      }
    }

    __syncthreads();
    if (t < 3) {
      #pragma unroll
      for (int i = 0; i < 5; ++i) {
        int e = tid + i * 256;
        if (e < 1048) {
          int r = e >> 2, c = e & 3;
          *(s16x8*)(lds + ((r * 64 + c * 16) ^ ((r & 7) << 4))) = xr[i];
        }
      }
    }
    __syncthreads();
  }
}

// ---------------------------------------------------------------------------
// conv3 persistent: full K=448 weights once; 6 pos-tiles of 128, T14 prefetch
// grid (2, 256); block = co64(half) x pos128; wave = 4m x 2n
// ---------------------------------------------------------------------------
__global__ __launch_bounds__(256) void k_conv3(
    const unsigned short* __restrict__ h2pt, const unsigned short* __restrict__ w3p,
    const float* __restrict__ cb, const float* __restrict__ bng,
    const float* __restrict__ bnb, unsigned short* __restrict__ h3pt)
{
  __shared__ __align__(16) char lds[75776];
  float* scs = (float*)(lds + 74752);
  const int tid = threadIdx.x, b = blockIdx.y, ch = blockIdx.x;
  const int cg0 = ch * 64;

  for (int e = tid; e < 3584; e += 256) {  // weights once: 64co x 56 chunks
    int co = e / 56, c = e % 56;
    s16x8 v = *(const s16x8*)(w3p + (cg0 + co) * 448 + c * 8);
    *(s16x8*)(lds + 17408 + ((co * 896 + c * 16) ^ ((co & 7) << 4))) = v;
  }
  if (tid < 64) {
    int co = cg0 + tid;
    float sc = bng[co] * BN_INV;
    scs[tid * 2] = sc;
    scs[tid * 2 + 1] = fmaf(cb[co], sc, bnb[co]);
  }
  {  // stage x tile 0 (l0=0): 134 rows x 8 chunks
    #pragma unroll
    for (int i = 0; i < 5; ++i) {
      int e = tid + i * 256;
      if (e < 1072) {
        int r = e >> 3, c = e & 7, gr = r - 3;
        s16x8 v;
        if (gr >= 0 && gr < 750) v = *(const s16x8*)(h2pt + (b * 750 + gr) * 64 + c * 8);
        else for (int q = 0; q < 8; ++q) v[q] = 0;
        *(s16x8*)(lds + ((r * 128 + c * 16) ^ ((r & 7) << 4))) = v;
      }
    }
  }
  __syncthreads();

  const int w = tid >> 6, l = tid & 63, lr = l & 15, g = l >> 4;
  const int wp = w * 32;

  for (int t = 0; t < 6; ++t) {
    const int l0 = t * 128;

    s16x8 xr[5];
    if (t < 5) {
      int nl0 = l0 + 128;
      #pragma unroll
      for (int i = 0; i < 5; ++i) {
        for (int q = 0; q < 8; ++q) xr[i][q] = 0;
        int e = tid + i * 256;
        if (e < 1072) {
          int r = e >> 3, c = e & 7, gr = nl0 - 3 + r;
          if (gr >= 0 && gr < 750)
            xr[i] = *(const s16x8*)(h2pt + (b * 750 + gr) * 64 + c * 8);
        }
      }
    }

    f32x4 acc[4][2];
    for (int m = 0; m < 4; ++m)
      for (int n = 0; n < 2; ++n)
        for (int i = 0; i < 4; ++i) acc[m][n][i] = 0.f;

    #pragma unroll
    for (int sl = 0; sl < 14; ++sl) {
      int kk = sl >> 1, cib = (sl & 1) * 32;
      s16x8 a[4], bf[2];
      #pragma unroll
      for (int m = 0; m < 4; ++m) {
        int co = m * 16 + lr;
        a[m] = *(const s16x8*)(lds + 17408 + ((co * 896 + sl * 64 + g * 16) ^ ((co & 7) << 4)));
      }
      #pragma unroll
      for (int n = 0; n < 2; ++n) {
        int row = wp + n * 16 + lr + kk;
        bf[n] = *(const s16x8*)(lds + ((row * 128 + cib * 2 + g * 16) ^ ((row & 7) << 4)));
      }
      #pragma unroll
      for (int m = 0; m < 4; ++m)
        #pragma unroll
        for (int n = 0; n < 2; ++n)
          acc[m][n] = __builtin_amdgcn_mfma_f32_16x16x32_bf16(a[m], bf[n], acc[m][n], 0, 0, 0);
    }

    #pragma unroll
    for (int m = 0; m < 4; ++m) {
      int co0 = m * 16 + g * 4;
      float sc[4], sh[4];
      #pragma unroll
      for (int j = 0; j < 4; ++j) { sc[j] = scs[(co0 + j) * 2]; sh[j] = scs[(co0 + j) * 2 + 1]; }
      #pragma unroll
      for (int n = 0; n < 2; ++n) {
        u16x4 o;
        #pragma unroll
        for (int j = 0; j < 4; ++j) {
          float tv = fmaxf(fmaf(acc[m][n][j], sc[j], sh[j]), 0.f);
          float t1 = fmaxf(tv, __shfl_xor(tv, 1));
          float t2 = fmaxf(t1, __shfl_xor(t1, 2));
          o[j] = f2bf(t2);
        }
        int pp = (l0 + wp + n * 16 + lr) >> 2;
        if ((l & 3) == 0 && pp < 187)
          *(u16x4*)(h3pt + (b * 187 + pp) * 128 + cg0 + co0) = o;
      }
    }

    __syncthreads();
    if (t < 5) {
      #pragma unroll
      for (int i = 0; i < 5; ++i) {
        int e = tid + i * 256;
        if (e < 1072) {
          int r = e >> 3, c = e & 7;
          *(s16x8*)(lds + ((r * 128 + c * 16) ^ ((r & 7) << 4))) = xr[i];
        }
      }
    }
    __syncthreads();
  }
}

// ---------------------------------------------------------------------------
// conv4: full x staged once (198 rows); 4 weight chunks of K=224 w/ T14
// grid (2 ch, 256 b); N=192; wave = co32(2m) x pos96(6n); sum -> atomicAdd h4
// ---------------------------------------------------------------------------
__global__ __launch_bounds__(256) void k_conv4(
    const unsigned short* __restrict__ h3pt, const unsigned short* __restrict__ w4p,
    const float* __restrict__ cb, const float* __restrict__ bng,
    const float* __restrict__ bnb, float* __restrict__ h4)
{
  __shared__ __align__(16) char lds[79872];
  float* scs = (float*)(lds + 79360);
  const int tid = threadIdx.x, b = blockIdx.y, ch = blockIdx.x;
  const int cg0 = ch * 64;

  // stage full x: 198 rows x 16 chunks
  #pragma unroll
  for (int i = 0; i < 13; ++i) {
    int e = tid + i * 256;
    if (e < 3168) {
      int r = e >> 4, c = e & 15, gr = r - 3;
      s16x8 v;
      if (gr >= 0 && gr < 187) v = *(const s16x8*)(h3pt + (b * 187 + gr) * 128 + c * 8);
      else for (int q = 0; q < 8; ++q) v[q] = 0;
      *(s16x8*)(lds + ((r * 256 + c * 16) ^ ((r & 7) << 4))) = v;
    }
  }
  for (int e = tid; e < 1792; e += 256) {  // weight chunk 0
    int co = e / 28, c = e % 28;
    s16x8 v = *(const s16x8*)(w4p + (cg0 + co) * 896 + c * 8);
    *(s16x8*)(lds + 50688 + ((co * 448 + c * 16) ^ ((co & 7) << 4))) = v;
  }
  if (tid < 64) {
    int co = cg0 + tid;
    float sc = bng[co] * BN_INV;
    scs[tid * 2] = sc;
    scs[tid * 2 + 1] = fmaf(cb[co], sc, bnb[co]);
  }
  __syncthreads();

  const int w = tid >> 6, l = tid & 63, lr = l & 15, g = l >> 4;
  const int co_off = (w & 1) * 32, pos_off = (w >> 1) * 96;

  f32x4 acc[2][6];
  for (int m = 0; m < 2; ++m)
    for (int n = 0; n < 6; ++n)
      for (int i = 0; i < 4; ++i) acc[m][n][i] = 0.f;

  for (int chunk = 0; chunk < 4; ++chunk) {
    s16x8 wr[7];
    if (chunk < 3) {  // T14: prefetch next weight chunk into regs
      #pragma unroll
      for (int i = 0; i < 7; ++i) {
        int e = tid + i * 256;
        int co = e / 28, c = e % 28;
        wr[i] = *(const s16x8*)(w4p + (cg0 + co) * 896 + (chunk + 1) * 224 + c * 8);
      }
    }
    #pragma unroll
    for (int sl = 0; sl < 7; ++sl) {
      int k0 = chunk * 224 + sl * 32;
      int kk = k0 >> 7, cib = k0 & 127;
      s16x8 a[2], bf[6];
      #pragma unroll
      for (int m = 0; m < 2; ++m) {
        int co = co_off + m * 16 + lr;
        a[m] = *(const s16x8*)(lds + 50688 + ((co * 448 + sl * 64 + g * 16) ^ ((co & 7) << 4)));
      }
      #pragma unroll
      for (int n = 0; n < 6; ++n) {
        int row = pos_off + n * 16 + lr + kk;
        bf[n] = *(const s16x8*)(lds + ((row * 256 + cib * 2 + g * 16) ^ ((row & 7) << 4)));
      }
      #pragma unroll
      for (int m = 0; m < 2; ++m)
        #pragma unroll
        for (int n = 0; n < 6; ++n)
          acc[m][n] = __builtin_amdgcn_mfma_f32_16x16x32_bf16(a[m], bf[n], acc[m][n], 0, 0, 0);
    }
    __syncthreads();
    if (chunk < 3) {
      #pragma unroll
      for (int i = 0; i < 7; ++i) {
        int e = tid + i * 256;
        int co = e / 28, c = e % 28;
        *(s16x8*)(lds + 50688 + ((co * 448 + c * 16) ^ ((co & 7) << 4))) = wr[i];
      }
    }
    __syncthreads();
  }

  float psum[2][4];
  for (int m = 0; m < 2; ++m)
    for (int j = 0; j < 4; ++j) psum[m][j] = 0.f;
  #pragma unroll
  for (int m = 0; m < 2; ++m) {
    int col = co_off + m * 16 + g * 4;
    #pragma unroll
    for (int n = 0; n < 6; ++n) {
      int pos_g = pos_off + n * 16 + lr;
      #pragma unroll
      for (int j = 0; j < 4; ++j) {
        float tv = fmaxf(fmaf(acc[m][n][j], scs[(col + j) * 2], scs[(col + j) * 2 + 1]), 0.f);
        if (pos_g < 187) psum[m][j] += tv;
      }
    }
  }
  #pragma unroll
  for (int m = 0; m < 2; ++m)
    #pragma unroll
    for (int j = 0; j < 4; ++j) {
      float v = psum[m][j];
      v += __shfl_xor(v, 1);
      v += __shfl_xor(v, 2);
      v += __shfl_xor(v, 4);
      v += __shfl_xor(v, 8);
      if (lr == 0)
        atomicAdd(&h4[b * 128 + cg0 + co_off + m * 16 + g * 4 + j], v);
    }
}

// ---------------------------------------------------------------------------
// head: one WAVE per batch; statevector in registers (4 amps/lane), all
// gates via shfl — zero barriers, zero LDS
// ---------------------------------------------------------------------------
__global__ __launch_bounds__(64) void k_head(
    const float* __restrict__ h4, const float* __restrict__ fc_w,
    const float* __restrict__ fc_b, const float* __restrict__ ang_w,
    const float* __restrict__ ang_b, const float* __restrict__ qw,
    const float* __restrict__ h1_w, const float* __restrict__ h1_b,
    const float* __restrict__ h2_w, const float* __restrict__ h2_b,
    float* __restrict__ out)
{
  const int lane = threadIdx.x;
  const int b = blockIdx.x;

  float hv0 = h4[b * 128 + lane] * (1.0f / 187.0f);
  float hv1 = h4[b * 128 + 64 + lane] * (1.0f / 187.0f);

  // fc 128->128: this lane computes outputs `lane` and `lane+64`
  float a0 = fc_b[lane], a1 = fc_b[lane + 64];
  {
    const float* w0 = fc_w + lane * 128;
    const float* w1 = fc_w + (lane + 64) * 128;
    #pragma unroll
    for (int k = 0; k < 64; ++k) {
      float hk = __shfl(hv0, k);
      a0 = fmaf(hk, w0[k], a0);
      a1 = fmaf(hk, w1[k], a1);
    }
    #pragma unroll
    for (int k = 0; k < 64; ++k) {
      float hk = __shfl(hv1, k);
      a0 = fmaf(hk, w0[64 + k], a0);
      a1 = fmaf(hk, w1[64 + k], a1);
    }
  }
  float f0 = fmaxf(a0, 0.f), f1 = fmaxf(a1, 0.f);

  // ang 128->8 (reduction form), then RY coefficients — all lanes hold all 8
  float rcw[8], rsw[8];
  #pragma unroll
  for (int o = 0; o < 8; ++o) {
    float p = fmaf(f0, ang_w[o * 128 + lane], f1 * ang_w[o * 128 + 64 + lane]);
    #pragma unroll
    for (int m = 1; m < 64; m <<= 1) p += __shfl_xor(p, m);
    float aa = PI_F * tanhf(ang_b[o] + p);
    rcw[o] = cosf(0.5f * aa);
    rsw[o] = sinf(0.5f * aa);
  }

  // Rot gate coefficients: lane (lane&15) computes gate (lane&15)
  float r0, r1, r2, r3, r4, r5, r6, r7;
  {
    int gq = lane & 15;
    float phi = qw[gq * 3], th = qw[gq * 3 + 1], om = qw[gq * 3 + 2];
    float cm = cosf(0.5f * th), sm = sinf(0.5f * th);
    float ap = 0.5f * (phi + om), bm = 0.5f * (phi - om);
    float ca = cosf(ap), sa = sinf(ap), cb2 = cosf(bm), sb2 = sinf(bm);
    r0 = cm * ca;   r1 = -cm * sa;
    r2 = -sm * cb2; r3 = -sm * sb2;
    r4 = sm * cb2;  r5 = -sm * sb2;
    r6 = cm * ca;   r7 = cm * sa;
  }

  // state: amp index a = lane*4 + j; wire w <-> bit (7-w); bits>=2 are lane bits
  float2 st[4];
  st[0] = make_float2((lane == 0) ? 1.f : 0.f, 0.f);
  st[1] = make_float2(0.f, 0.f);
  st[2] = make_float2(0.f, 0.f);
  st[3] = make_float2(0.f, 0.f);

  auto ry_lane = [&](int lx, float c, float s) {
    #pragma unroll
    for (int j = 0; j < 4; ++j) {
      float ox = __shfl_xor(st[j].x, lx);
      float oy = __shfl_xor(st[j].y, lx);
      bool hi = (lane & lx) != 0;
      float a0x = hi ? ox : st[j].x, a0y = hi ? oy : st[j].y;
      float a1x = hi ? st[j].x : ox, a1y = hi ? st[j].y : oy;
      float cA = hi ? s : c, cB = hi ? c : -s;
      st[j].x = cA * a0x + cB * a1x;
      st[j].y = cA * a0y + cB * a1y;
    }
  };
#define RY_SLOT(J0, J1, c, s) { \
    float2 A = st[J0], B = st[J1]; \
    st[J0].x = (c) * A.x - (s) * B.x; st[J0].y = (c) * A.y - (s) * B.y; \
    st[J1].x = (s) * A.x + (c) * B.x; st[J1].y = (s) * A.y + (c) * B.y; }

  // AngleEmbedding: RY on wires 0..7
  ry_lane(32, rcw[0], rsw[0]);
  ry_lane(16, rcw[1], rsw[1]);
  ry_lane(8,  rcw[2], rsw[2]);
  ry_lane(4,  rcw[3], rsw[3]);
  ry_lane(2,  rcw[4], rsw[4]);
  ry_lane(1,  rcw[5], rsw[5]);
  RY_SLOT(0, 2, rcw[6], rsw[6]); RY_SLOT(1, 3, rcw[6], rsw[6]);
  RY_SLOT(0, 1, rcw[7], rsw[7]); RY_SLOT(2, 3, rcw[7], rsw[7]);

  auto rot_lane = [&](int gi, int lx) {
    float m00x = __shfl(r0, gi), m00y = __shfl(r1, gi);
    float m01x = __shfl(r2, gi), m01y = __shfl(r3, gi);
    float m10x = __shfl(r4, gi), m10y = __shfl(r5, gi);
    float m11x = __shfl(r6, gi), m11y = __shfl(r7, gi);
    #pragma unroll
    for (int j = 0; j < 4; ++j) {
      float ox = __shfl_xor(st[j].x, lx);
      float oy = __shfl_xor(st[j].y, lx);
      bool hi = (lane & lx) != 0;
      float a0x = hi ? ox : st[j].x, a0y = hi ? oy : st[j].y;
      float a1x = hi ? st[j].x : ox, a1y = hi ? st[j].y : oy;
      float cx = hi ? m10x : m00x, cy = hi ? m10y : m00y;
      float dx = hi ? m11x : m01x, dy = hi ? m11y : m01y;
      st[j].x = cx * a0x - cy * a0y + dx * a1x - dy * a1y;
      st[j].y = cx * a0y + cy * a0x + dx * a1y + dy * a1x;
    }
  };
#define ROT_SLOT(J0, J1) { \
    float2 A = st[J0], B = st[J1]; \
    st[J0].x = m00x * A.x - m00y * A.y + m01x * B.x - m01y * B.y; \
    st[J0].y = m00x * A.y + m00y * A.x + m01x * B.y + m01y * B.x; \
    st[J1].x = m10x * A.x - m10y * A.y + m11x * B.x - m11y * B.y; \
    st[J1].y = m10x * A.y + m10y * A.x + m11x * B.y + m11y * B.x; }
  auto rot_slot = [&](int gi, int bit) {
    float m00x = __shfl(r0, gi), m00y = __shfl(r1, gi);
    float m01x = __shfl(r2, gi), m01y = __shfl(r3, gi);
    float m10x = __shfl(r4, gi), m10y = __shfl(r5, gi);
    float m11x = __shfl(r6, gi), m11y = __shfl(r7, gi);
    if (bit == 1) { ROT_SLOT(0, 2) ROT_SLOT(1, 3) }
    else          { ROT_SLOT(0, 1) ROT_SLOT(2, 3) }
  };

  auto cnot = [&](int cmask, int tmask) {
    bool cb0, cb1, cb2, cb3;
    if (cmask >= 4) {
      bool cbl = (lane & (cmask >> 2)) != 0;
      cb0 = cbl; cb1 = cbl; cb2 = cbl; cb3 = cbl;
    } else {
      cb0 = false;
      cb1 = (1 & cmask) != 0;
      cb2 = (2 & cmask) != 0;
      cb3 = (3 & cmask) != 0;
    }
    if (tmask >= 4) {
      int lx = tmask >> 2;
      { float ox = __shfl_xor(st[0].x, lx), oy = __shfl_xor(st[0].y, lx); if (cb0) { st[0].x = ox; st[0].y = oy; } }
      { float ox = __shfl_xor(st[1].x, lx), oy = __shfl_xor(st[1].y, lx); if (cb1) { st[1].x = ox; st[1].y = oy; } }
      { float ox = __shfl_xor(st[2].x, lx), oy = __shfl_xor(st[2].y, lx); if (cb2) { st[2].x = ox; st[2].y = oy; } }
      { float ox = __shfl_xor(st[3].x, lx), oy = __shfl_xor(st[3].y, lx); if (cb3) { st[3].x = ox; st[3].y = oy; } }
    } else {
      float2 o0 = st[0], o1 = st[1], o2 = st[2], o3 = st[3];
      if (tmask == 2) {
        if (cb0) st[0] = o2;
        if (cb1) st[1] = o3;
        if (cb2) st[2] = o0;
        if (cb3) st[3] = o1;
      } else {
        if (cb0) st[0] = o1;
        if (cb1) st[1] = o0;
        if (cb2) st[2] = o3;
        if (cb3) st[3] = o2;
      }
    }
  };

  // StronglyEntanglingLayers: 2 layers x (8 Rot + 8 CNOT ring, r = l+1)
  #pragma unroll
  for (int lay = 0; lay < 2; ++lay) {
    rot_lane(lay * 8 + 0, 32);
    rot_lane(lay * 8 + 1, 16);
    rot_lane(lay * 8 + 2, 8);
    rot_lane(lay * 8 + 3, 4);
    rot_lane(lay * 8 + 4, 2);
    rot_lane(lay * 8 + 5, 1);
    rot_slot(lay * 8 + 6, 1);
    rot_slot(lay * 8 + 7, 0);
    int r = lay + 1;
    #pragma unroll
    for (int i = 0; i < 8; ++i) {
      int c = i, t = (i + r) & 7;
      cnot(1 << (7 - c), 1 << (7 - t));
    }
  }

  // <Z_w> expectations
  float p0 = st[0].x * st[0].x + st[0].y * st[0].y;
  float p1 = st[1].x * st[1].x + st[1].y * st[1].y;
  float p2 = st[2].x * st[2].x + st[2].y * st[2].y;
  float p3 = st[3].x * st[3].x + st[3].y * st[3].y;
  float sAll = p0 + p1 + p2 + p3;
  float zp[8];
  zp[0] = (lane & 32) ? -sAll : sAll;
  zp[1] = (lane & 16) ? -sAll : sAll;
  zp[2] = (lane & 8)  ? -sAll : sAll;
  zp[3] = (lane & 4)  ? -sAll : sAll;
  zp[4] = (lane & 2)  ? -sAll : sAll;
  zp[5] = (lane & 1)  ? -sAll : sAll;
  zp[6] = (p0 + p1) - (p2 + p3);
  zp[7] = (p0 - p1) + (p2 - p3);
  #pragma unroll
  for (int o = 0; o < 8; ++o) {
    #pragma unroll
    for (int m = 1; m < 64; m <<= 1) zp[o] += __shfl_xor(zp[o], m);
  }

  // h1: 64 outputs, one per lane
  float ah = h1_b[lane];
  const float* hw = h1_w + lane * 8;
  #pragma unroll
  for (int k = 0; k < 8; ++k) ah = fmaf(zp[k], hw[k], ah);
  float hh = fmaxf(ah, 0.f);

  // h2: 5 outputs via wave reductions
  #pragma unroll
  for (int o = 0; o < 5; ++o) {
    float v = hh * h2_w[o * 64 + lane];
    #pragma unroll
    for (int m = 1; m < 64; m <<= 1) v += __shfl_xor(v, m);
    if (lane == 0) out[b * 5 + o] = v + h2_b[o];
  }
#undef RY_SLOT
#undef ROT_SLOT
}

// ---------------------------------------------------------------------------
extern "C" void kernel_launch(void* const* d_in, const int* in_sizes, int n_in,
                              void* d_out, int out_size, void* d_ws, size_t ws_size,
                              hipStream_t stream) {
  (void)in_sizes; (void)n_in; (void)out_size; (void)ws_size;
  const float* x    = (const float*)d_in[0];
  const float* c1w  = (const float*)d_in[1];
  const float* c1b  = (const float*)d_in[2];
  const float* b1g  = (const float*)d_in[3];
  const float* b1b  = (const float*)d_in[4];
  const float* c2w  = (const float*)d_in[5];
  const float* c2b  = (const float*)d_in[6];
  const float* b2g  = (const float*)d_in[7];
  const float* b2b  = (const float*)d_in[8];
  const float* c3w  = (const float*)d_in[9];
  const float* c3b  = (const float*)d_in[10];
  const float* b3g  = (const float*)d_in[11];
  const float* b3b  = (const float*)d_in[12];
  const float* c4w  = (const float*)d_in[13];
  const float* c4b  = (const float*)d_in[14];
  const float* b4g  = (const float*)d_in[15];
  const float* b4b  = (const float*)d_in[16];
  const float* fcw  = (const float*)d_in[17];
  const float* fcb  = (const float*)d_in[18];
  const float* angw = (const float*)d_in[19];
  const float* angb = (const float*)d_in[20];
  const float* qw   = (const float*)d_in[21];
  const float* h1w  = (const float*)d_in[22];
  const float* h1b  = (const float*)d_in[23];
  const float* h2w  = (const float*)d_in[24];
  const float* h2b  = (const float*)d_in[25];

  char* wsb = (char*)d_ws;
  unsigned short* w1p  = (unsigned short*)(wsb + 0);        // 4096 B
  unsigned short* w2p  = (unsigned short*)(wsb + 4096);     // 28672 B
  unsigned short* w3p  = (unsigned short*)(wsb + 32768);    // 114688 B
  unsigned short* w4p  = (unsigned short*)(wsb + 147456);   // 229376 B
  float*          h4   = (float*)(wsb + 393216);            // 131072 B
  unsigned short* h1t  = (unsigned short*)(wsb + 1048576);  // 49.15 MB
  unsigned short* h2pt = (unsigned short*)(wsb + 52428800); // 24.58 MB
  unsigned short* h3pt = (unsigned short*)(wsb + 79691776); // 12.25 MB

  k_pack<<<dim3(864), 256, 0, stream>>>(c1w, c2w, c3w, c4w, w1p, w2p, w3p, w4p, h4);
  k_conv1<<<dim3(6, 256), 256, 0, stream>>>(x, w1p, c1b, b1g, b1b, h1t);
  k_conv2<<<dim3(3, 256), 256, 0, stream>>>(h1t, w2p, c2b, b2g, b2b, h2pt);
  k_conv3<<<dim3(2, 256), 256, 0, stream>>>(h2pt, w3p, c3b, b3g, b3b, h3pt);
  k_conv4<<<dim3(2, 256), 256, 0, stream>>>(h3pt, w4p, c4b, b4g, b4b, h4);
  k_head<<<dim3(256), 64, 0, stream>>>(h4, fcw, fcb, angw, angb, qw,
                                       h1w, h1b, h2w, h2b, (float*)d_out);
}

// Round 4
// 229.608 us; speedup vs baseline: 1.0969x; 1.0969x over previous
//
#include <hip/hip_runtime.h>
#include <hip/hip_bf16.h>

#define BN_INV 0.9999950000375f   // 1/sqrt(1+1e-5)
#define PI_F   3.14159265358979f

typedef __attribute__((ext_vector_type(8))) short s16x8;
typedef __attribute__((ext_vector_type(4))) float f32x4;
typedef __attribute__((ext_vector_type(4))) unsigned short u16x4;

__device__ inline unsigned short f2bf(float f) {
  union { float f; unsigned u; } v; v.f = f;
  unsigned r = v.u + 0x7fffu + ((v.u >> 16) & 1u);
  return (unsigned short)(r >> 16);
}

// ---------------------------------------------------------------------------
// pack: fp32 conv weights -> bf16 packed [co][k], k = kk*Ci_pad + ci
// also zero h4 (conv4 accumulates with atomics)
// ---------------------------------------------------------------------------
__global__ __launch_bounds__(256) void k_pack(
    const float* __restrict__ w1, const float* __restrict__ w2,
    const float* __restrict__ w3, const float* __restrict__ w4,
    unsigned short* __restrict__ w1p, unsigned short* __restrict__ w2p,
    unsigned short* __restrict__ w3p, unsigned short* __restrict__ w4p,
    float* __restrict__ h4)
{
  int e = blockIdx.x * 256 + threadIdx.x;
  if (e < 2048) {
    int co = e >> 6, k = e & 63, kk = k >> 3, ci = k & 7;
    w1p[e] = (ci < 4 && kk < 7) ? f2bf(w1[co * 28 + ci * 7 + kk]) : (unsigned short)0;
  } else if (e < 16384) {
    int t = e - 2048; int co = t / 224, k = t % 224, kk = k >> 5, ci = k & 31;
    w2p[t] = f2bf(w2[co * 224 + ci * 7 + kk]);
  } else if (e < 73728) {
    int t = e - 16384; int co = t / 448, k = t % 448, kk = k >> 6, ci = k & 63;
    w3p[t] = f2bf(w3[co * 448 + ci * 7 + kk]);
  } else if (e < 188416) {
    int t = e - 73728; int co = t / 896, k = t % 896, kk = k >> 7, ci = k & 127;
    w4p[t] = f2bf(w4[co * 896 + ci * 7 + kk]);
  } else if (e < 221184) {
    h4[e - 188416] = 0.f;
  }
}

// ---------------------------------------------------------------------------
// conv1 MFMA: x fp32 (256,4,3000) -> h1t bf16 [b][3000][32], BN+ReLU
// ---------------------------------------------------------------------------
__global__ __launch_bounds__(256) void k_conv1(
    const float* __restrict__ x, const unsigned short* __restrict__ w1p,
    const float* __restrict__ cb, const float* __restrict__ bng,
    const float* __restrict__ bnb, unsigned short* __restrict__ h1t)
{
  __shared__ __align__(16) char lds[520 * 16 + 4096 + 256];
  float* scs = (float*)(lds + 520 * 16 + 4096);
  const int tid = threadIdx.x;
  const int b = blockIdx.y;
  const int l0 = blockIdx.x * 512;

  for (int r = tid; r < 519; r += 256) {
    int gr = l0 + r - 3;
    s16x8 v;
    if (gr >= 0 && gr < 3000) {
      const float* xr = x + b * 4 * 3000 + gr;
      v[0] = (short)f2bf(xr[0]);
      v[1] = (short)f2bf(xr[3000]);
      v[2] = (short)f2bf(xr[6000]);
      v[3] = (short)f2bf(xr[9000]);
      v[4] = 0; v[5] = 0; v[6] = 0; v[7] = 0;
    } else {
      for (int i = 0; i < 8; ++i) v[i] = 0;
    }
    *(s16x8*)(lds + r * 16) = v;
  }
  {
    int co = tid >> 3, c = tid & 7;
    s16x8 v = *(const s16x8*)(w1p + co * 64 + c * 8);
    *(s16x8*)(lds + 8320 + ((co * 128 + c * 16) ^ ((co & 7) << 4))) = v;
  }
  if (tid < 32) {
    float sc = bng[tid] * BN_INV;
    scs[tid * 2] = sc;
    scs[tid * 2 + 1] = fmaf(cb[tid], sc, bnb[tid]);
  }
  __syncthreads();

  const int w = tid >> 6, l = tid & 63, lr = l & 15, g = l >> 4;
  const int wp = w * 128;
  f32x4 acc[2][8];
  for (int m = 0; m < 2; ++m)
    for (int n = 0; n < 8; ++n)
      for (int i = 0; i < 4; ++i) acc[m][n][i] = 0.f;

  #pragma unroll
  for (int s = 0; s < 2; ++s) {
    s16x8 a[2], bf[8];
    #pragma unroll
    for (int m = 0; m < 2; ++m) {
      int co = m * 16 + lr;
      a[m] = *(const s16x8*)(lds + 8320 + ((co * 128 + s * 64 + g * 16) ^ ((co & 7) << 4)));
    }
    #pragma unroll
    for (int n = 0; n < 8; ++n) {
      int row = wp + n * 16 + lr + s * 4 + g;
      bf[n] = *(const s16x8*)(lds + row * 16);
    }
    #pragma unroll
    for (int m = 0; m < 2; ++m)
      #pragma unroll
      for (int n = 0; n < 8; ++n)
        acc[m][n] = __builtin_amdgcn_mfma_f32_16x16x32_bf16(a[m], bf[n], acc[m][n], 0, 0, 0);
  }

  #pragma unroll
  for (int m = 0; m < 2; ++m) {
    int co0 = m * 16 + g * 4;
    float sc[4], sh[4];
    #pragma unroll
    for (int j = 0; j < 4; ++j) { sc[j] = scs[(co0 + j) * 2]; sh[j] = scs[(co0 + j) * 2 + 1]; }
    #pragma unroll
    for (int n = 0; n < 8; ++n) {
      int gp = l0 + wp + n * 16 + lr;
      if (gp < 3000) {
        u16x4 o;
        #pragma unroll
        for (int j = 0; j < 4; ++j)
          o[j] = f2bf(fmaxf(fmaf(acc[m][n][j], sc[j], sh[j]), 0.f));
        *(u16x4*)(h1t + (b * 3000 + gp) * 32 + co0) = o;
      }
    }
  }
}

// ---------------------------------------------------------------------------
// conv2 MFMA (operand-swapped): h1t -> BN+ReLU+pool4 -> h2pt [b][750][64]
// grid (12, 256); block: pos256 x co64; wave = pos64(4m) x co64(4n); K=224
// C-layout: row = position (regs), col = co (lanes) -> pool in registers
// ---------------------------------------------------------------------------
__global__ __launch_bounds__(256) void k_conv2(
    const unsigned short* __restrict__ h1t, const unsigned short* __restrict__ w2p,
    const float* __restrict__ cb, const float* __restrict__ bng,
    const float* __restrict__ bnb, unsigned short* __restrict__ h2pt)
{
  __shared__ __align__(16) char lds[46080];
  float* scs = (float*)(lds + 45568);
  const int tid = threadIdx.x, b = blockIdx.y;
  const int l0 = blockIdx.x * 256;

  for (int e = tid; e < 1048; e += 256) {  // x: 262 rows x 4 chunks
    int r = e >> 2, c = e & 3;
    int gr = l0 + r - 3;
    s16x8 v;
    if (gr >= 0 && gr < 3000) v = *(const s16x8*)(h1t + (b * 3000 + gr) * 32 + c * 8);
    else for (int i = 0; i < 8; ++i) v[i] = 0;
    *(s16x8*)(lds + ((r * 64 + c * 16) ^ ((r & 7) << 4))) = v;
  }
  for (int e = tid; e < 1792; e += 256) {  // weights: 64co x 28 chunks
    int co = e / 28, c = e % 28;
    s16x8 v = *(const s16x8*)(w2p + co * 224 + c * 8);
    *(s16x8*)(lds + 16896 + ((co * 448 + c * 16) ^ ((co & 7) << 4))) = v;
  }
  if (tid < 64) {
    float sc = bng[tid] * BN_INV;
    scs[tid * 2] = sc;
    scs[tid * 2 + 1] = fmaf(cb[tid], sc, bnb[tid]);
  }
  __syncthreads();

  const int w = tid >> 6, l = tid & 63, lr = l & 15, g = l >> 4;
  const int wp = w * 64;
  f32x4 acc[4][4];
  for (int m = 0; m < 4; ++m)
    for (int n = 0; n < 4; ++n)
      for (int i = 0; i < 4; ++i) acc[m][n][i] = 0.f;

  #pragma unroll
  for (int s = 0; s < 7; ++s) {
    s16x8 xa[4], wb[4];
    #pragma unroll
    for (int m = 0; m < 4; ++m) {
      int row = wp + m * 16 + lr + s;
      xa[m] = *(const s16x8*)(lds + ((row * 64 + g * 16) ^ ((row & 7) << 4)));
    }
    #pragma unroll
    for (int n = 0; n < 4; ++n) {
      int co = n * 16 + lr;
      wb[n] = *(const s16x8*)(lds + 16896 + ((co * 448 + s * 64 + g * 16) ^ ((co & 7) << 4)));
    }
    #pragma unroll
    for (int m = 0; m < 4; ++m)
      #pragma unroll
      for (int n = 0; n < 4; ++n)
        acc[m][n] = __builtin_amdgcn_mfma_f32_16x16x32_bf16(xa[m], wb[n], acc[m][n], 0, 0, 0);
  }

  float sc[4], sh[4];
  #pragma unroll
  for (int n = 0; n < 4; ++n) {
    sc[n] = scs[(n * 16 + lr) * 2];
    sh[n] = scs[(n * 16 + lr) * 2 + 1];
  }
  #pragma unroll
  for (int m = 0; m < 4; ++m) {
    int pp = (l0 + wp + m * 16 + g * 4) >> 2;
    if (pp < 750) {
      unsigned short* orow = h2pt + (b * 750 + pp) * 64 + lr;
      #pragma unroll
      for (int n = 0; n < 4; ++n) {
        float v = fmaxf(fmaxf(acc[m][n][0], acc[m][n][1]),
                        fmaxf(acc[m][n][2], acc[m][n][3]));
        orow[n * 16] = f2bf(fmaxf(fmaf(v, sc[n], sh[n]), 0.f));
      }
    }
  }
}

// ---------------------------------------------------------------------------
// conv3 MFMA (operand-swapped): h2pt -> BN+ReLU+pool4 -> h3pt [b][187][128]
// grid (12, 256): tile(128 pos) x co-half(64); wave = pos32(2m) x co64(4n)
// full K=448 weights staged once per block
// ---------------------------------------------------------------------------
__global__ __launch_bounds__(256) void k_conv3(
    const unsigned short* __restrict__ h2pt, const unsigned short* __restrict__ w3p,
    const float* __restrict__ cb, const float* __restrict__ bng,
    const float* __restrict__ bnb, unsigned short* __restrict__ h3pt)
{
  __shared__ __align__(16) char lds[75776];
  float* scs = (float*)(lds + 74752);
  const int tid = threadIdx.x, b = blockIdx.y;
  const int tile = blockIdx.x >> 1, ch = blockIdx.x & 1;
  const int l0 = tile * 128, cg0 = ch * 64;

  for (int e = tid; e < 1072; e += 256) {  // x: 134 rows x 8 chunks
    int r = e >> 3, c = e & 7;
    int gr = l0 + r - 3;
    s16x8 v;
    if (gr >= 0 && gr < 750) v = *(const s16x8*)(h2pt + (b * 750 + gr) * 64 + c * 8);
    else for (int i = 0; i < 8; ++i) v[i] = 0;
    *(s16x8*)(lds + ((r * 128 + c * 16) ^ ((r & 7) << 4))) = v;
  }
  for (int e = tid; e < 3584; e += 256) {  // weights: 64co x 56 chunks (K=448)
    int co = e / 56, c = e % 56;
    s16x8 v = *(const s16x8*)(w3p + (cg0 + co) * 448 + c * 8);
    *(s16x8*)(lds + 17408 + ((co * 896 + c * 16) ^ ((co & 7) << 4))) = v;
  }
  if (tid < 64) {
    int co = cg0 + tid;
    float sc = bng[co] * BN_INV;
    scs[tid * 2] = sc;
    scs[tid * 2 + 1] = fmaf(cb[co], sc, bnb[co]);
  }
  __syncthreads();

  const int w = tid >> 6, l = tid & 63, lr = l & 15, g = l >> 4;
  const int wp = w * 32;
  f32x4 acc[2][4];
  for (int m = 0; m < 2; ++m)
    for (int n = 0; n < 4; ++n)
      for (int i = 0; i < 4; ++i) acc[m][n][i] = 0.f;

  #pragma unroll
  for (int sl = 0; sl < 14; ++sl) {
    int kk = sl >> 1, cib = (sl & 1) * 32;
    s16x8 xa[2], wb[4];
    #pragma unroll
    for (int m = 0; m < 2; ++m) {
      int row = wp + m * 16 + lr + kk;
      xa[m] = *(const s16x8*)(lds + ((row * 128 + cib * 2 + g * 16) ^ ((row & 7) << 4)));
    }
    #pragma unroll
    for (int n = 0; n < 4; ++n) {
      int co = n * 16 + lr;
      wb[n] = *(const s16x8*)(lds + 17408 + ((co * 896 + sl * 64 + g * 16) ^ ((co & 7) << 4)));
    }
    #pragma unroll
    for (int m = 0; m < 2; ++m)
      #pragma unroll
      for (int n = 0; n < 4; ++n)
        acc[m][n] = __builtin_amdgcn_mfma_f32_16x16x32_bf16(xa[m], wb[n], acc[m][n], 0, 0, 0);
  }

  float sc[4], sh[4];
  #pragma unroll
  for (int n = 0; n < 4; ++n) {
    sc[n] = scs[(n * 16 + lr) * 2];
    sh[n] = scs[(n * 16 + lr) * 2 + 1];
  }
  #pragma unroll
  for (int m = 0; m < 2; ++m) {
    int pp = (l0 + wp + m * 16 + g * 4) >> 2;
    if (pp < 187) {
      unsigned short* orow = h3pt + (b * 187 + pp) * 128 + cg0 + lr;
      #pragma unroll
      for (int n = 0; n < 4; ++n) {
        float v = fmaxf(fmaxf(acc[m][n][0], acc[m][n][1]),
                        fmaxf(acc[m][n][2], acc[m][n][3]));
        orow[n * 16] = f2bf(fmaxf(fmaf(v, sc[n], sh[n]), 0.f));
      }
    }
  }
}

// ---------------------------------------------------------------------------
// conv4 (operand-swapped): h3pt -> BN+ReLU -> masked mean -> atomicAdd h4
// grid (2 ch, 256 b); block: pos192 x co64; wave = pos48(3m) x co64(4n)
// full x staged once; 4 weight chunks of K=224 with T14 reg prefetch
// ---------------------------------------------------------------------------
__global__ __launch_bounds__(256) void k_conv4(
    const unsigned short* __restrict__ h3pt, const unsigned short* __restrict__ w4p,
    const float* __restrict__ cb, const float* __restrict__ bng,
    const float* __restrict__ bnb, float* __restrict__ h4)
{
  __shared__ __align__(16) char lds[79872];
  float* scs = (float*)(lds + 79360);
  const int tid = threadIdx.x, b = blockIdx.y, ch = blockIdx.x;
  const int cg0 = ch * 64;

  #pragma unroll
  for (int i = 0; i < 13; ++i) {  // x: 198 rows x 16 chunks
    int e = tid + i * 256;
    if (e < 3168) {
      int r = e >> 4, c = e & 15, gr = r - 3;
      s16x8 v;
      if (gr >= 0 && gr < 187) v = *(const s16x8*)(h3pt + (b * 187 + gr) * 128 + c * 8);
      else for (int q = 0; q < 8; ++q) v[q] = 0;
      *(s16x8*)(lds + ((r * 256 + c * 16) ^ ((r & 7) << 4))) = v;
    }
  }
  for (int e = tid; e < 1792; e += 256) {  // weight chunk 0
    int co = e / 28, c = e % 28;
    s16x8 v = *(const s16x8*)(w4p + (cg0 + co) * 896 + c * 8);
    *(s16x8*)(lds + 50688 + ((co * 448 + c * 16) ^ ((co & 7) << 4))) = v;
  }
  if (tid < 64) {
    int co = cg0 + tid;
    float sc = bng[co] * BN_INV;
    scs[tid * 2] = sc;
    scs[tid * 2 + 1] = fmaf(cb[co], sc, bnb[co]);
  }
  __syncthreads();

  const int w = tid >> 6, l = tid & 63, lr = l & 15, g = l >> 4;
  const int wp = w * 48;

  f32x4 acc[3][4];
  for (int m = 0; m < 3; ++m)
    for (int n = 0; n < 4; ++n)
      for (int i = 0; i < 4; ++i) acc[m][n][i] = 0.f;

  for (int chunk = 0; chunk < 4; ++chunk) {
    s16x8 wr[7];
    if (chunk < 3) {  // T14: prefetch next weight chunk into regs
      #pragma unroll
      for (int i = 0; i < 7; ++i) {
        int e = tid + i * 256;
        int co = e / 28, c = e % 28;
        wr[i] = *(const s16x8*)(w4p + (cg0 + co) * 896 + (chunk + 1) * 224 + c * 8);
      }
    }
    #pragma unroll
    for (int sl = 0; sl < 7; ++sl) {
      int k0 = chunk * 224 + sl * 32;
      int kk = k0 >> 7, cib = k0 & 127;
      s16x8 xa[3], wb[4];
      #pragma unroll
      for (int m = 0; m < 3; ++m) {
        int row = wp + m * 16 + lr + kk;
        xa[m] = *(const s16x8*)(lds + ((row * 256 + cib * 2 + g * 16) ^ ((row & 7) << 4)));
      }
      #pragma unroll
      for (int n = 0; n < 4; ++n) {
        int co = n * 16 + lr;
        wb[n] = *(const s16x8*)(lds + 50688 + ((co * 448 + sl * 64 + g * 16) ^ ((co & 7) << 4)));
      }
      #pragma unroll
      for (int m = 0; m < 3; ++m)
        #pragma unroll
        for (int n = 0; n < 4; ++n)
          acc[m][n] = __builtin_amdgcn_mfma_f32_16x16x32_bf16(xa[m], wb[n], acc[m][n], 0, 0, 0);
    }
    __syncthreads();
    if (chunk < 3) {
      #pragma unroll
      for (int i = 0; i < 7; ++i) {
        int e = tid + i * 256;
        int co = e / 28, c = e % 28;
        *(s16x8*)(lds + 50688 + ((co * 448 + c * 16) ^ ((co & 7) << 4))) = wr[i];
      }
    }
    __syncthreads();
  }

  float sc[4], sh[4];
  #pragma unroll
  for (int n = 0; n < 4; ++n) {
    sc[n] = scs[(n * 16 + lr) * 2];
    sh[n] = scs[(n * 16 + lr) * 2 + 1];
  }
  float psum[4] = {0.f, 0.f, 0.f, 0.f};
  #pragma unroll
  for (int m = 0; m < 3; ++m) {
    #pragma unroll
    for (int j = 0; j < 4; ++j) {
      int pos = wp + m * 16 + g * 4 + j;
      if (pos < 187) {
        #pragma unroll
        for (int n = 0; n < 4; ++n)
          psum[n] += fmaxf(fmaf(acc[m][n][j], sc[n], sh[n]), 0.f);
      }
    }
  }
  #pragma unroll
  for (int n = 0; n < 4; ++n) {
    float v = psum[n];
    v += __shfl_xor(v, 16);
    v += __shfl_xor(v, 32);
    if (l < 16)
      atomicAdd(&h4[b * 128 + cg0 + n * 16 + lr], v);
  }
}

// ---------------------------------------------------------------------------
// head: one WAVE per batch; statevector in registers (4 amps/lane), all
// gates via shfl — zero barriers, zero LDS
// ---------------------------------------------------------------------------
__global__ __launch_bounds__(64) void k_head(
    const float* __restrict__ h4, const float* __restrict__ fc_w,
    const float* __restrict__ fc_b, const float* __restrict__ ang_w,
    const float* __restrict__ ang_b, const float* __restrict__ qw,
    const float* __restrict__ h1_w, const float* __restrict__ h1_b,
    const float* __restrict__ h2_w, const float* __restrict__ h2_b,
    float* __restrict__ out)
{
  const int lane = threadIdx.x;
  const int b = blockIdx.x;

  float hv0 = h4[b * 128 + lane] * (1.0f / 187.0f);
  float hv1 = h4[b * 128 + 64 + lane] * (1.0f / 187.0f);

  float a0 = fc_b[lane], a1 = fc_b[lane + 64];
  {
    const float* w0 = fc_w + lane * 128;
    const float* w1 = fc_w + (lane + 64) * 128;
    #pragma unroll
    for (int k = 0; k < 64; ++k) {
      float hk = __shfl(hv0, k);
      a0 = fmaf(hk, w0[k], a0);
      a1 = fmaf(hk, w1[k], a1);
    }
    #pragma unroll
    for (int k = 0; k < 64; ++k) {
      float hk = __shfl(hv1, k);
      a0 = fmaf(hk, w0[64 + k], a0);
      a1 = fmaf(hk, w1[64 + k], a1);
    }
  }
  float f0 = fmaxf(a0, 0.f), f1 = fmaxf(a1, 0.f);

  float rcw[8], rsw[8];
  #pragma unroll
  for (int o = 0; o < 8; ++o) {
    float p = fmaf(f0, ang_w[o * 128 + lane], f1 * ang_w[o * 128 + 64 + lane]);
    #pragma unroll
    for (int m = 1; m < 64; m <<= 1) p += __shfl_xor(p, m);
    float aa = PI_F * tanhf(ang_b[o] + p);
    rcw[o] = cosf(0.5f * aa);
    rsw[o] = sinf(0.5f * aa);
  }

  float r0, r1, r2, r3, r4, r5, r6, r7;
  {
    int gq = lane & 15;
    float phi = qw[gq * 3], th = qw[gq * 3 + 1], om = qw[gq * 3 + 2];
    float cm = cosf(0.5f * th), sm = sinf(0.5f * th);
    float ap = 0.5f * (phi + om), bm = 0.5f * (phi - om);
    float ca = cosf(ap), sa = sinf(ap), cb2 = cosf(bm), sb2 = sinf(bm);
    r0 = cm * ca;   r1 = -cm * sa;
    r2 = -sm * cb2; r3 = -sm * sb2;
    r4 = sm * cb2;  r5 = -sm * sb2;
    r6 = cm * ca;   r7 = cm * sa;
  }

  float2 st[4];
  st[0] = make_float2((lane == 0) ? 1.f : 0.f, 0.f);
  st[1] = make_float2(0.f, 0.f);
  st[2] = make_float2(0.f, 0.f);
  st[3] = make_float2(0.f, 0.f);

  auto ry_lane = [&](int lx, float c, float s) {
    #pragma unroll
    for (int j = 0; j < 4; ++j) {
      float ox = __shfl_xor(st[j].x, lx);
      float oy = __shfl_xor(st[j].y, lx);
      bool hi = (lane & lx) != 0;
      float a0x = hi ? ox : st[j].x, a0y = hi ? oy : st[j].y;
      float a1x = hi ? st[j].x : ox, a1y = hi ? st[j].y : oy;
      float cA = hi ? s : c, cB = hi ? c : -s;
      st[j].x = cA * a0x + cB * a1x;
      st[j].y = cA * a0y + cB * a1y;
    }
  };
#define RY_SLOT(J0, J1, c, s) { \
    float2 A = st[J0], B = st[J1]; \
    st[J0].x = (c) * A.x - (s) * B.x; st[J0].y = (c) * A.y - (s) * B.y; \
    st[J1].x = (s) * A.x + (c) * B.x; st[J1].y = (s) * A.y + (c) * B.y; }

  ry_lane(32, rcw[0], rsw[0]);
  ry_lane(16, rcw[1], rsw[1]);
  ry_lane(8,  rcw[2], rsw[2]);
  ry_lane(4,  rcw[3], rsw[3]);
  ry_lane(2,  rcw[4], rsw[4]);
  ry_lane(1,  rcw[5], rsw[5]);
  RY_SLOT(0, 2, rcw[6], rsw[6]); RY_SLOT(1, 3, rcw[6], rsw[6]);
  RY_SLOT(0, 1, rcw[7], rsw[7]); RY_SLOT(2, 3, rcw[7], rsw[7]);

  auto rot_lane = [&](int gi, int lx) {
    float m00x = __shfl(r0, gi), m00y = __shfl(r1, gi);
    float m01x = __shfl(r2, gi), m01y = __shfl(r3, gi);
    float m10x = __shfl(r4, gi), m10y = __shfl(r5, gi);
    float m11x = __shfl(r6, gi), m11y = __shfl(r7, gi);
    #pragma unroll
    for (int j = 0; j < 4; ++j) {
      float ox = __shfl_xor(st[j].x, lx);
      float oy = __shfl_xor(st[j].y, lx);
      bool hi = (lane & lx) != 0;
      float a0x = hi ? ox : st[j].x, a0y = hi ? oy : st[j].y;
      float a1x = hi ? st[j].x : ox, a1y = hi ? st[j].y : oy;
      float cx = hi ? m10x : m00x, cy = hi ? m10y : m00y;
      float dx = hi ? m11x : m01x, dy = hi ? m11y : m01y;
      st[j].x = cx * a0x - cy * a0y + dx * a1x - dy * a1y;
      st[j].y = cx * a0y + cy * a0x + dx * a1y + dy * a1x;
    }
  };
#define ROT_SLOT(J0, J1) { \
    float2 A = st[J0], B = st[J1]; \
    st[J0].x = m00x * A.x - m00y * A.y + m01x * B.x - m01y * B.y; \
    st[J0].y = m00x * A.y + m00y * A.x + m01x * B.y + m01y * B.x; \
    st[J1].x = m10x * A.x - m10y * A.y + m11x * B.x - m11y * B.y; \
    st[J1].y = m10x * A.y + m10y * A.x + m11x * B.y + m11y * B.x; }
  auto rot_slot = [&](int gi, int bit) {
    float m00x = __shfl(r0, gi), m00y = __shfl(r1, gi);
    float m01x = __shfl(r2, gi), m01y = __shfl(r3, gi);
    float m10x = __shfl(r4, gi), m10y = __shfl(r5, gi);
    float m11x = __shfl(r6, gi), m11y = __shfl(r7, gi);
    if (bit == 1) { ROT_SLOT(0, 2) ROT_SLOT(1, 3) }
    else          { ROT_SLOT(0, 1) ROT_SLOT(2, 3) }
  };

  auto cnot = [&](int cmask, int tmask) {
    bool cb0, cb1, cb2, cb3;
    if (cmask >= 4) {
      bool cbl = (lane & (cmask >> 2)) != 0;
      cb0 = cbl; cb1 = cbl; cb2 = cbl; cb3 = cbl;
    } else {
      cb0 = false;
      cb1 = (1 & cmask) != 0;
      cb2 = (2 & cmask) != 0;
      cb3 = (3 & cmask) != 0;
    }
    if (tmask >= 4) {
      int lx = tmask >> 2;
      { float ox = __shfl_xor(st[0].x, lx), oy = __shfl_xor(st[0].y, lx); if (cb0) { st[0].x = ox; st[0].y = oy; } }
      { float ox = __shfl_xor(st[1].x, lx), oy = __shfl_xor(st[1].y, lx); if (cb1) { st[1].x = ox; st[1].y = oy; } }
      { float ox = __shfl_xor(st[2].x, lx), oy = __shfl_xor(st[2].y, lx); if (cb2) { st[2].x = ox; st[2].y = oy; } }
      { float ox = __shfl_xor(st[3].x, lx), oy = __shfl_xor(st[3].y, lx); if (cb3) { st[3].x = ox; st[3].y = oy; } }
    } else {
      float2 o0 = st[0], o1 = st[1], o2 = st[2], o3 = st[3];
      if (tmask == 2) {
        if (cb0) st[0] = o2;
        if (cb1) st[1] = o3;
        if (cb2) st[2] = o0;
        if (cb3) st[3] = o1;
      } else {
        if (cb0) st[0] = o1;
        if (cb1) st[1] = o0;
        if (cb2) st[2] = o3;
        if (cb3) st[3] = o2;
      }
    }
  };

  #pragma unroll
  for (int lay = 0; lay < 2; ++lay) {
    rot_lane(lay * 8 + 0, 32);
    rot_lane(lay * 8 + 1, 16);
    rot_lane(lay * 8 + 2, 8);
    rot_lane(lay * 8 + 3, 4);
    rot_lane(lay * 8 + 4, 2);
    rot_lane(lay * 8 + 5, 1);
    rot_slot(lay * 8 + 6, 1);
    rot_slot(lay * 8 + 7, 0);
    int r = lay + 1;
    #pragma unroll
    for (int i = 0; i < 8; ++i) {
      int c = i, t = (i + r) & 7;
      cnot(1 << (7 - c), 1 << (7 - t));
    }
  }

  float p0 = st[0].x * st[0].x + st[0].y * st[0].y;
  float p1 = st[1].x * st[1].x + st[1].y * st[1].y;
  float p2 = st[2].x * st[2].x + st[2].y * st[2].y;
  float p3 = st[3].x * st[3].x + st[3].y * st[3].y;
  float sAll = p0 + p1 + p2 + p3;
  float zp[8];
  zp[0] = (lane & 32) ? -sAll : sAll;
  zp[1] = (lane & 16) ? -sAll : sAll;
  zp[2] = (lane & 8)  ? -sAll : sAll;
  zp[3] = (lane & 4)  ? -sAll : sAll;
  zp[4] = (lane & 2)  ? -sAll : sAll;
  zp[5] = (lane & 1)  ? -sAll : sAll;
  zp[6] = (p0 + p1) - (p2 + p3);
  zp[7] = (p0 - p1) + (p2 - p3);
  #pragma unroll
  for (int o = 0; o < 8; ++o) {
    #pragma unroll
    for (int m = 1; m < 64; m <<= 1) zp[o] += __shfl_xor(zp[o], m);
  }

  float ah = h1_b[lane];
  const float* hw = h1_w + lane * 8;
  #pragma unroll
  for (int k = 0; k < 8; ++k) ah = fmaf(zp[k], hw[k], ah);
  float hh = fmaxf(ah, 0.f);

  #pragma unroll
  for (int o = 0; o < 5; ++o) {
    float v = hh * h2_w[o * 64 + lane];
    #pragma unroll
    for (int m = 1; m < 64; m <<= 1) v += __shfl_xor(v, m);
    if (lane == 0) out[b * 5 + o] = v + h2_b[o];
  }
#undef RY_SLOT
#undef ROT_SLOT
}

// ---------------------------------------------------------------------------
extern "C" void kernel_launch(void* const* d_in, const int* in_sizes, int n_in,
                              void* d_out, int out_size, void* d_ws, size_t ws_size,
                              hipStream_t stream) {
  (void)in_sizes; (void)n_in; (void)out_size; (void)ws_size;
  const float* x    = (const float*)d_in[0];
  const float* c1w  = (const float*)d_in[1];
  const float* c1b  = (const float*)d_in[2];
  const float* b1g  = (const float*)d_in[3];
  const float* b1b  = (const float*)d_in[4];
  const float* c2w  = (const float*)d_in[5];
  const float* c2b  = (const float*)d_in[6];
  const float* b2g  = (const float*)d_in[7];
  const float* b2b  = (const float*)d_in[8];
  const float* c3w  = (const float*)d_in[9];
  const float* c3b  = (const float*)d_in[10];
  const float* b3g  = (const float*)d_in[11];
  const float* b3b  = (const float*)d_in[12];
  const float* c4w  = (const float*)d_in[13];
  const float* c4b  = (const float*)d_in[14];
  const float* b4g  = (const float*)d_in[15];
  const float* b4b  = (const float*)d_in[16];
  const float* fcw  = (const float*)d_in[17];
  const float* fcb  = (const float*)d_in[18];
  const float* angw = (const float*)d_in[19];
  const float* angb = (const float*)d_in[20];
  const float* qw   = (const float*)d_in[21];
  const float* h1w  = (const float*)d_in[22];
  const float* h1b  = (const float*)d_in[23];
  const float* h2w  = (const float*)d_in[24];
  const float* h2b  = (const float*)d_in[25];

  char* wsb = (char*)d_ws;
  unsigned short* w1p  = (unsigned short*)(wsb + 0);        // 4096 B
  unsigned short* w2p  = (unsigned short*)(wsb + 4096);     // 28672 B
  unsigned short* w3p  = (unsigned short*)(wsb + 32768);    // 114688 B
  unsigned short* w4p  = (unsigned short*)(wsb + 147456);   // 229376 B
  float*          h4   = (float*)(wsb + 393216);            // 131072 B
  unsigned short* h1t  = (unsigned short*)(wsb + 1048576);  // 49.15 MB
  unsigned short* h2pt = (unsigned short*)(wsb + 52428800); // 24.58 MB
  unsigned short* h3pt = (unsigned short*)(wsb + 79691776); // 12.25 MB

  k_pack<<<dim3(864), 256, 0, stream>>>(c1w, c2w, c3w, c4w, w1p, w2p, w3p, w4p, h4);
  k_conv1<<<dim3(6, 256),  256, 0, stream>>>(x, w1p, c1b, b1g, b1b, h1t);
  k_conv2<<<dim3(12, 256), 256, 0, stream>>>(h1t, w2p, c2b, b2g, b2b, h2pt);
  k_conv3<<<dim3(12, 256), 256, 0, stream>>>(h2pt, w3p, c3b, b3g, b3b, h3pt);
  k_conv4<<<dim3(2, 256),  256, 0, stream>>>(h3pt, w4p, c4b, b4g, b4b, h4);
  k_head<<<dim3(256), 64, 0, stream>>>(h4, fcw, fcb, angw, angb, qw,
                                       h1w, h1b, h2w, h2b, (float*)d_out);
}